// Round 3
// baseline (59044.763 us; speedup 1.0000x reference)
//
#include <hip/hip_runtime.h>
#include <math.h>

// 2-layer tanh RNN, B=64 T=1024 I=256 H=512, fp32.
//   xp  = x @ W_ih^T + (b_ih + b_hh)      (GEMM, parallel)
//   h_t = tanh(xp_t + h_{t-1} @ W_hh^T)   (sequential scan)
//   out = h2[:,-1,:] @ fc_W^T + fc_b
//
// Recurrence: W_hh LDS-resident, 8 slices x 64 rows (128KB LDS) -> 1 block/CU,
// grid = 32 pairs x 8 slices = 256 = #CUs (all co-resident -> spin-sync safe).
// Slices of a pair exchange h via Infinity Cache (agent-scope atomics), gated
// by a monotonic per-pair arrival counter. Double-buffered hxc + arrive-then-
// read ordering => no WAR hazard (a writer of parity q at step t+2 has
// observed every reader of step t pass counter t+1).
//
// WS-ADAPTIVE CHUNKING (round-2 fix: never assume ws_size): time is processed
// in chunks of C steps, C = largest pow2 with 2*C*131072 + ~0.7MB <= ws_size.
// Per chunk: proj0 -> scan0 -> proj1 -> scan1. xp buffer P reused for xp0/xp1;
// h carries across launches via hxc (kernel boundary = full ordering).
//
// WS layout: P[C*64*512 f32] | Hc[C*64*512 f32] | h2last 128KB | hxcA 256KB |
//            hxcB 256KB | ctr 128B

#define B_  64
#define T_  1024
#define H_  512
#define JS  64      // rows per slice = H_/8

// ------- projection GEMM: Cout[m][512] = A[row(m)][K] @ W[512][K]^T + (bi+bh)
// Row mapping m -> (b = m>>lgC, lt = m&(C-1)), A row = b*Tfull + t0 + lt.
// For x: Tfull=1024, t0=chunk start. For chunk-local Hc: Tfull=C, t0=0 (row=m).
template<int K>
__global__ __launch_bounds__(256)
void proj_gemm(const float* __restrict__ A, const float* __restrict__ W,
               const float* __restrict__ bi, const float* __restrict__ bh,
               float* __restrict__ Cout, int lgC, int t0, int Tfull)
{
    __shared__ float As[32*132];   // [k][m], padded
    __shared__ float Bs[32*68];    // [k][n], padded
    const int tid = threadIdx.x;
    const int m0 = blockIdx.x * 128;
    const int n0 = blockIdx.y * 64;
    const int ty = tid >> 4;          // 0..15 -> 8 rows each
    const int tx = tid & 15;          // 0..15 -> 4 cols each
    const int lr = tid >> 3;          // 0..31 staging row
    const int lk = (tid & 7) * 4;     // staging k-offset
    const int Cm = (1 << lgC) - 1;

    float acc[8][4];
    #pragma unroll
    for (int i = 0; i < 8; ++i)
        #pragma unroll
        for (int j = 0; j < 4; ++j) acc[i][j] = 0.f;

    for (int k0 = 0; k0 < K; k0 += 32) {
        #pragma unroll
        for (int p = 0; p < 4; ++p) {          // A tile 128x32
            int r = p*32 + lr;
            int m = m0 + r;
            int b = m >> lgC, lt = m & Cm;
            size_t row = (size_t)b * Tfull + t0 + lt;
            float4 v = *reinterpret_cast<const float4*>(&A[row*K + k0 + lk]);
            As[(lk+0)*132 + r] = v.x;  As[(lk+1)*132 + r] = v.y;
            As[(lk+2)*132 + r] = v.z;  As[(lk+3)*132 + r] = v.w;
        }
        #pragma unroll
        for (int p = 0; p < 2; ++p) {          // W tile 64x32
            int r = p*32 + lr;
            float4 v = *reinterpret_cast<const float4*>(&W[(size_t)(n0 + r)*K + k0 + lk]);
            Bs[(lk+0)*68 + r] = v.x;  Bs[(lk+1)*68 + r] = v.y;
            Bs[(lk+2)*68 + r] = v.z;  Bs[(lk+3)*68 + r] = v.w;
        }
        __syncthreads();
        #pragma unroll
        for (int k = 0; k < 32; ++k) {
            float4 a0 = *reinterpret_cast<const float4*>(&As[k*132 + ty*8]);
            float4 a1 = *reinterpret_cast<const float4*>(&As[k*132 + ty*8 + 4]);
            float4 bv = *reinterpret_cast<const float4*>(&Bs[k*68 + tx*4]);
            float av[8] = {a0.x,a0.y,a0.z,a0.w,a1.x,a1.y,a1.z,a1.w};
            float bb[4] = {bv.x,bv.y,bv.z,bv.w};
            #pragma unroll
            for (int i = 0; i < 8; ++i)
                #pragma unroll
                for (int j = 0; j < 4; ++j) acc[i][j] += av[i]*bb[j];
        }
        __syncthreads();
    }
    float4 bias;
    bias.x = bi[n0+tx*4+0] + bh[n0+tx*4+0];
    bias.y = bi[n0+tx*4+1] + bh[n0+tx*4+1];
    bias.z = bi[n0+tx*4+2] + bh[n0+tx*4+2];
    bias.w = bi[n0+tx*4+3] + bh[n0+tx*4+3];
    #pragma unroll
    for (int i = 0; i < 8; ++i) {
        int m = m0 + ty*8 + i;
        float4 v = { acc[i][0]+bias.x, acc[i][1]+bias.y,
                     acc[i][2]+bias.z, acc[i][3]+bias.w };
        *reinterpret_cast<float4*>(&Cout[(size_t)m*H_ + n0 + tx*4]) = v;
    }
}

// ------- recurrent scan over one chunk of Csteps --------------------------
// block = (pair p, slice s): batches {2p,2p+1}, rows [64s,64s+64).
// LDS: Wt[512][64] (128KB) + hli[512][2] + red[2][4][64]. xp/hist chunk-local.
__global__ __launch_bounds__(256)
void rnn_scan(const float* __restrict__ Whh, const float* __restrict__ xp,
              float* __restrict__ hist, float* __restrict__ hlast,
              float* hxc, unsigned int* ctr, unsigned int base,
              int t0, int Csteps)
{
    extern __shared__ float lds[];
    float* Wt  = lds;                  // [k][jl]  512*64
    float* hli = lds + 32768;          // [k][b]   512*2
    float* red = lds + 32768 + 1024;   // [b][kg][jl] 2*4*64

    const int tid = threadIdx.x;
    const int p   = blockIdx.x >> 3;
    const int s   = blockIdx.x & 7;
    const int b0  = p * 2;
    const int j0  = s * JS;

    // Stage W slice transposed (one-time; amortized over Csteps).
    for (int e = tid*4; e < JS*H_; e += 256*4) {
        int jl = e >> 9, k = e & 511;
        float4 w = *reinterpret_cast<const float4*>(&Whh[(size_t)(j0+jl)*H_ + k]);
        Wt[(k+0)*JS + jl] = w.x;  Wt[(k+1)*JS + jl] = w.y;
        Wt[(k+2)*JS + jl] = w.z;  Wt[(k+3)*JS + jl] = w.w;
    }
    // h state: zero at t=0, else reload last chunk's h from hxc (parity of t0-1;
    // kernel boundary ordered the stores).
    if (t0 == 0) {
        for (int e = tid; e < 2*H_; e += 256) hli[e] = 0.f;
    } else {
        int par = (t0 - 1) & 1;
        const float* src = &hxc[((size_t)par*B_ + b0) * H_];
        #pragma unroll
        for (int i = 0; i < 4; ++i) {
            int e = tid + i*256;
            int b = e >> 9, k = e & 511;
            hli[k*2 + b] = __hip_atomic_load(&src[(size_t)b*H_ + k],
                                             __ATOMIC_RELAXED, __HIP_MEMORY_SCOPE_AGENT);
        }
    }
    __syncthreads();

    const int jl = tid & 63;
    const int kg = tid >> 6;       // k-group 0..3, 128 k's each
    const int kb = kg * 128;
    const int wb = tid >> 6;       // for tid<128: batch index 0/1

    for (int lt = 0; lt < Csteps; ++lt) {
        const int tg = t0 + lt;
        // prefetch xp (chunk-local row b*Csteps+lt)
        float xpv = 0.f;
        if (tid < 128) {
            size_t m = (size_t)(b0 + wb) * Csteps + lt;
            xpv = xp[m * H_ + j0 + (tid & 63)];
        }
        // dot phase: Wt[k*64+jl] = 2-way bank alias (free); hli = broadcast.
        float s00=0.f, s01=0.f, s10=0.f, s11=0.f;
        #pragma unroll 8
        for (int kk = 0; kk < 128; kk += 2) {
            int k = kb + kk;
            float w0 = Wt[(k+0)*JS + jl];
            float w1 = Wt[(k+1)*JS + jl];
            float2 h0 = *reinterpret_cast<const float2*>(&hli[(k+0)*2]);
            float2 h1 = *reinterpret_cast<const float2*>(&hli[(k+1)*2]);
            s00 += w0*h0.x;  s01 += w0*h0.y;
            s10 += w1*h1.x;  s11 += w1*h1.y;
        }
        red[(0*4 + kg)*64 + jl] = s00 + s10;
        red[(1*4 + kg)*64 + jl] = s01 + s11;
        __syncthreads();                                   // (1)

        if (tid < 128) {
            int j = tid & 63;
            float y = red[(wb*4+0)*64+j] + red[(wb*4+1)*64+j]
                    + red[(wb*4+2)*64+j] + red[(wb*4+3)*64+j] + xpv;
            float h = tanhf(y);
            size_t m = (size_t)(b0 + wb) * Csteps + lt;
            if (hist) hist[m * H_ + j0 + j] = h;
            if (hlast && lt == Csteps-1) hlast[(size_t)(b0+wb)*H_ + j0 + j] = h;
            __hip_atomic_store(&hxc[((size_t)(tg&1)*B_ + b0 + wb)*H_ + j0 + j], h,
                               __ATOMIC_RELAXED, __HIP_MEMORY_SCOPE_AGENT);
        }
        __threadfence();        // drain agent stores before counter bump
        __syncthreads();                                   // (2)

        if (lt < Csteps-1) {
            if (tid == 0) {
                __hip_atomic_fetch_add(&ctr[p], 1u,
                                       __ATOMIC_RELAXED, __HIP_MEMORY_SCOPE_AGENT);
                unsigned target = base + 8u*(unsigned)(lt+1);
                while (__hip_atomic_load(&ctr[p], __ATOMIC_RELAXED,
                                         __HIP_MEMORY_SCOPE_AGENT) < target)
                    __builtin_amdgcn_s_sleep(1);
                __threadfence();
            }
            __syncthreads();                               // (3)
            const float* src = &hxc[((size_t)(tg&1)*B_ + b0) * H_];
            #pragma unroll
            for (int i = 0; i < 4; ++i) {
                int e = tid + i*256;           // 0..1023
                int b = e >> 9, k = e & 511;
                float v = __hip_atomic_load(&src[(size_t)b*H_ + k],
                                            __ATOMIC_RELAXED, __HIP_MEMORY_SCOPE_AGENT);
                hli[k*2 + b] = v;
            }
            __syncthreads();                               // (4)
        }
    }
}

// ------- tiny FC head -----------------------------------------------------
__global__ __launch_bounds__(64)
void fc_kernel(const float* __restrict__ hl, const float* __restrict__ fw,
               const float* __restrict__ fb, float* __restrict__ out)
{
    int b = blockIdx.x, tid = threadIdx.x;
    float p0 = 0.f, p1 = 0.f;
    #pragma unroll
    for (int i = 0; i < 8; ++i) {
        int k = tid + i*64;
        float h = hl[(size_t)b*H_ + k];
        p0 += h * fw[k];
        p1 += h * fw[H_ + k];
    }
    #pragma unroll
    for (int off = 32; off > 0; off >>= 1) {
        p0 += __shfl_down(p0, off, 64);
        p1 += __shfl_down(p1, off, 64);
    }
    if (tid == 0) {
        out[b*2+0] = p0 + fb[0];
        out[b*2+1] = p1 + fb[1];
    }
}

extern "C" void kernel_launch(void* const* d_in, const int* in_sizes, int n_in,
                              void* d_out, int out_size, void* d_ws, size_t ws_size,
                              hipStream_t stream)
{
    const float* x    = (const float*)d_in[0];
    const float* Wih0 = (const float*)d_in[1];
    const float* Whh0 = (const float*)d_in[2];
    const float* bih0 = (const float*)d_in[3];
    const float* bhh0 = (const float*)d_in[4];
    const float* Wih1 = (const float*)d_in[5];
    const float* Whh1 = (const float*)d_in[6];
    const float* bih1 = (const float*)d_in[7];
    const float* bhh1 = (const float*)d_in[8];
    const float* fcW  = (const float*)d_in[9];
    const float* fcb  = (const float*)d_in[10];
    float* out = (float*)d_out;

    // ---- ws-adaptive chunk size (ws_size is constant per session -> same
    // work every call; graph-capture safe).
    const size_t EXTRA = 1u << 20;   // h2last+hxcA+hxcB+ctr = 655,616 B, rounded
    int C = 1024;
    while (C > 16 && (2*(size_t)C*131072 + EXTRA) > ws_size) C >>= 1;
    int lgC = 0; { int t = C; while (t > 1) { t >>= 1; ++lgC; } }

    char* ws = (char*)d_ws;
    size_t S = (size_t)C * 131072;             // one chunk buffer (C*64*512 f32)
    float*        P      = (float*)ws;          // xp0 then xp1 (per chunk)
    float*        Hc     = (float*)(ws + S);    // h1 chunk
    char*         sm     = ws + 2*S;
    float*        h2last = (float*)sm;                       // 128 KB
    float*        hxcA   = (float*)(sm + 131072);            // 256 KB (layer 0)
    float*        hxcB   = (float*)(sm + 131072 + 262144);   // 256 KB (layer 1)
    unsigned int* ctr    = (unsigned int*)(sm + 131072 + 2*262144);

    const int LDS_BYTES = (32768 + 1024 + 512) * 4;   // 137216 B -> 1 block/CU
    hipFuncSetAttribute(reinterpret_cast<const void*>(rnn_scan),
                        hipFuncAttributeMaxDynamicSharedMemorySize, LDS_BYTES);

    hipMemsetAsync(ctr, 0, 128, stream);

    unsigned basev = 0;
    const int nch = T_ / C;
    for (int c = 0; c < nch; ++c) {
        const int t0 = c * C;
        // xp0 chunk = x[:, t0:t0+C, :] @ Wih0^T + bias
        proj_gemm<256><<<dim3(C/2, 8), 256, 0, stream>>>(x, Wih0, bih0, bhh0,
                                                         P, lgC, t0, T_);
        // layer-0 scan chunk -> h1 chunk
        rnn_scan<<<256, 256, LDS_BYTES, stream>>>(Whh0, P, Hc, nullptr,
                                                  hxcA, ctr, basev, t0, C);
        basev += 8u * (C - 1);
        // xp1 chunk = h1chunk @ Wih1^T + bias (overwrites P)
        proj_gemm<512><<<dim3(C/2, 8), 256, 0, stream>>>(Hc, Wih1, bih1, bhh1,
                                                         P, lgC, 0, C);
        // layer-1 scan chunk; final h2 only on last chunk
        rnn_scan<<<256, 256, LDS_BYTES, stream>>>(Whh1, P, nullptr,
                                                  (c == nch-1) ? h2last : nullptr,
                                                  hxcB, ctr, basev, t0, C);
        basev += 8u * (C - 1);
    }
    fc_kernel<<<64, 64, 0, stream>>>(h2last, fcW, fcb, out);
}

// Round 4
// 10571.944 us; speedup vs baseline: 5.5850x; 5.5850x over previous
//
#include <hip/hip_runtime.h>
#include <math.h>

// 2-layer tanh RNN, B=64 T=1024 I=256 H=512, fp32.
//   xp  = x @ W_ih^T + (b_ih + b_hh)      (GEMM, parallel)
//   h_t = tanh(xp_t + h_{t-1} @ W_hh^T)   (sequential scan)
//   out = h2[:,-1,:] @ fc_W^T + fc_b
//
// Recurrence: W_hh LDS-resident, 8 slices x 64 rows (128KB LDS) -> 1 block/CU,
// grid = 32 pairs x 8 slices = 256 = #CUs (all co-resident -> spin-sync safe).
// ROUND-4 SYNC REWRITE (r3 counters: VALUBusy 1.9%, FETCH 300MB -> threadfence
// L2-invalidate thrash + RMW counter chain was ~98% of time):
//  - NO __threadfence (no buffer_inv/wbl2). h stores are agent sc1 stores;
//    __syncthreads() drains vmcnt(0) for all waves = release ordering.
//  - NO fetch_add. Per-slice monotonic flag (= global step+1), plain agent
//    atomic store after the drain-barrier; readers poll 8 flags with 8 lanes,
//    then __syncthreads orders the subsequent exchange loads (IC serializes:
//    a load issued after the gating flag-load completed sees the h stores
//    that preceded the flag).
//  - Exchange reads widened to 8B atomics.
// Double-buffered hxc (parity on global step) + arrive-then-read => no WAR.
//
// WS layout: P[C*64*512 f32] | Hc[C*64*512 f32] | h2last 128KB | hxcA 256KB |
//            hxcB 256KB | flags[2][32][8] u32 (2KB)

#define B_  64
#define T_  1024
#define H_  512
#define JS  64      // rows per slice = H_/8

// ------- projection GEMM: Cout[m][512] = A[row(m)][K] @ W[512][K]^T + (bi+bh)
// Row mapping m -> (b = m>>lgC, lt = m&(C-1)), A row = b*Tfull + t0 + lt.
template<int K>
__global__ __launch_bounds__(256)
void proj_gemm(const float* __restrict__ A, const float* __restrict__ W,
               const float* __restrict__ bi, const float* __restrict__ bh,
               float* __restrict__ Cout, int lgC, int t0, int Tfull)
{
    __shared__ float As[32*132];   // [k][m], padded
    __shared__ float Bs[32*68];    // [k][n], padded
    const int tid = threadIdx.x;
    const int m0 = blockIdx.x * 128;
    const int n0 = blockIdx.y * 64;
    const int ty = tid >> 4;
    const int tx = tid & 15;
    const int lr = tid >> 3;
    const int lk = (tid & 7) * 4;
    const int Cm = (1 << lgC) - 1;

    float acc[8][4];
    #pragma unroll
    for (int i = 0; i < 8; ++i)
        #pragma unroll
        for (int j = 0; j < 4; ++j) acc[i][j] = 0.f;

    for (int k0 = 0; k0 < K; k0 += 32) {
        #pragma unroll
        for (int p = 0; p < 4; ++p) {          // A tile 128x32
            int r = p*32 + lr;
            int m = m0 + r;
            int b = m >> lgC, lt = m & Cm;
            size_t row = (size_t)b * Tfull + t0 + lt;
            float4 v = *reinterpret_cast<const float4*>(&A[row*K + k0 + lk]);
            As[(lk+0)*132 + r] = v.x;  As[(lk+1)*132 + r] = v.y;
            As[(lk+2)*132 + r] = v.z;  As[(lk+3)*132 + r] = v.w;
        }
        #pragma unroll
        for (int p = 0; p < 2; ++p) {          // W tile 64x32
            int r = p*32 + lr;
            float4 v = *reinterpret_cast<const float4*>(&W[(size_t)(n0 + r)*K + k0 + lk]);
            Bs[(lk+0)*68 + r] = v.x;  Bs[(lk+1)*68 + r] = v.y;
            Bs[(lk+2)*68 + r] = v.z;  Bs[(lk+3)*68 + r] = v.w;
        }
        __syncthreads();
        #pragma unroll
        for (int k = 0; k < 32; ++k) {
            float4 a0 = *reinterpret_cast<const float4*>(&As[k*132 + ty*8]);
            float4 a1 = *reinterpret_cast<const float4*>(&As[k*132 + ty*8 + 4]);
            float4 bv = *reinterpret_cast<const float4*>(&Bs[k*68 + tx*4]);
            float av[8] = {a0.x,a0.y,a0.z,a0.w,a1.x,a1.y,a1.z,a1.w};
            float bb[4] = {bv.x,bv.y,bv.z,bv.w};
            #pragma unroll
            for (int i = 0; i < 8; ++i)
                #pragma unroll
                for (int j = 0; j < 4; ++j) acc[i][j] += av[i]*bb[j];
        }
        __syncthreads();
    }
    float4 bias;
    bias.x = bi[n0+tx*4+0] + bh[n0+tx*4+0];
    bias.y = bi[n0+tx*4+1] + bh[n0+tx*4+1];
    bias.z = bi[n0+tx*4+2] + bh[n0+tx*4+2];
    bias.w = bi[n0+tx*4+3] + bh[n0+tx*4+3];
    #pragma unroll
    for (int i = 0; i < 8; ++i) {
        int m = m0 + ty*8 + i;
        float4 v = { acc[i][0]+bias.x, acc[i][1]+bias.y,
                     acc[i][2]+bias.z, acc[i][3]+bias.w };
        *reinterpret_cast<float4*>(&Cout[(size_t)m*H_ + n0 + tx*4]) = v;
    }
}

// ------- recurrent scan over one chunk of Csteps --------------------------
// block = (pair p, slice s): batches {2p,2p+1}, rows [64s,64s+64).
// LDS: Wt[512][64] (128KB) + hli[512][2] + red[2][4][64].
__global__ __launch_bounds__(256)
void rnn_scan(const float* __restrict__ Whh, const float* __restrict__ xp,
              float* __restrict__ hist, float* __restrict__ hlast,
              float* hxc, unsigned int* flags, int t0, int Csteps)
{
    extern __shared__ float lds[];
    float* Wt  = lds;                  // [k][jl]  512*64
    float* hli = lds + 32768;          // [k][b]   512*2
    float* red = lds + 32768 + 1024;   // [b][kg][jl] 2*4*64

    const int tid = threadIdx.x;
    const int p   = blockIdx.x >> 3;
    const int s   = blockIdx.x & 7;
    const int b0  = p * 2;
    const int j0  = s * JS;
    unsigned int* flagp = flags + p*8;

    // Stage W slice transposed (one-time; amortized over Csteps).
    for (int e = tid*4; e < JS*H_; e += 256*4) {
        int jl = e >> 9, k = e & 511;
        float4 w = *reinterpret_cast<const float4*>(&Whh[(size_t)(j0+jl)*H_ + k]);
        Wt[(k+0)*JS + jl] = w.x;  Wt[(k+1)*JS + jl] = w.y;
        Wt[(k+2)*JS + jl] = w.z;  Wt[(k+3)*JS + jl] = w.w;
    }
    // h state: zero at t=0, else reload last chunk's h (parity of t0-1;
    // kernel boundary ordered those stores).
    if (t0 == 0) {
        for (int e = tid; e < 2*H_; e += 256) hli[e] = 0.f;
    } else {
        int par = (t0 - 1) & 1;
        const float* src = &hxc[((size_t)par*B_ + b0) * H_];
        #pragma unroll
        for (int i = 0; i < 4; ++i) {
            int e = tid + i*256;
            int b = e >> 9, k = e & 511;
            hli[k*2 + b] = __hip_atomic_load(&src[(size_t)b*H_ + k],
                                             __ATOMIC_RELAXED, __HIP_MEMORY_SCOPE_AGENT);
        }
    }
    __syncthreads();

    const int jl = tid & 63;
    const int kg = tid >> 6;       // k-group 0..3, 128 k's each
    const int kb = kg * 128;
    const int wb = tid >> 6;       // for tid<128: batch index 0/1

    for (int lt = 0; lt < Csteps; ++lt) {
        const int tg = t0 + lt;
        // prefetch xp (normal cached load -- L2 is never invalidated now)
        float xpv = 0.f;
        if (tid < 128) {
            size_t m = (size_t)(b0 + wb) * Csteps + lt;
            xpv = xp[m * H_ + j0 + (tid & 63)];
        }
        // dot phase: Wt[k*64+jl] = 2-way bank alias (free); hli = broadcast.
        float s00=0.f, s01=0.f, s10=0.f, s11=0.f;
        #pragma unroll 8
        for (int kk = 0; kk < 128; kk += 2) {
            int k = kb + kk;
            float w0 = Wt[(k+0)*JS + jl];
            float w1 = Wt[(k+1)*JS + jl];
            float2 h0 = *reinterpret_cast<const float2*>(&hli[(k+0)*2]);
            float2 h1 = *reinterpret_cast<const float2*>(&hli[(k+1)*2]);
            s00 += w0*h0.x;  s01 += w0*h0.y;
            s10 += w1*h1.x;  s11 += w1*h1.y;
        }
        red[(0*4 + kg)*64 + jl] = s00 + s10;
        red[(1*4 + kg)*64 + jl] = s01 + s11;
        __syncthreads();                                   // (1)

        if (tid < 128) {
            int j = tid & 63;
            float y = red[(wb*4+0)*64+j] + red[(wb*4+1)*64+j]
                    + red[(wb*4+2)*64+j] + red[(wb*4+3)*64+j] + xpv;
            float h = tanhf(y);
            size_t m = (size_t)(b0 + wb) * Csteps + lt;
            if (hist) hist[m * H_ + j0 + j] = h;
            if (hlast && lt == Csteps-1) hlast[(size_t)(b0+wb)*H_ + j0 + j] = h;
            __hip_atomic_store(&hxc[((size_t)(tg&1)*B_ + b0 + wb)*H_ + j0 + j], h,
                               __ATOMIC_RELAXED, __HIP_MEMORY_SCOPE_AGENT);
        }
        // Barrier (2): compiler-emitted s_waitcnt vmcnt(0) before s_barrier
        // drains BOTH writer waves' sc1 stores -> h is at the IC for the
        // whole block. This IS the release fence; no cache maintenance.
        __syncthreads();                                   // (2)
        // Publish: this slice finished global step tg.
        if (tid == 0)
            __hip_atomic_store(&flagp[s], (unsigned)(tg + 1),
                               __ATOMIC_RELAXED, __HIP_MEMORY_SCOPE_AGENT);

        if (lt < Csteps-1) {
            // 8 lanes poll the pair's 8 per-slice flags in parallel.
            if (tid < 8) {
                const unsigned target = (unsigned)(tg + 1);
                while (__hip_atomic_load(&flagp[tid], __ATOMIC_RELAXED,
                                         __HIP_MEMORY_SCOPE_AGENT) < target)
                    __builtin_amdgcn_s_sleep(1);
            }
            __syncthreads();                               // (3)
            // Exchange: read all 8 slices' h (8B atomics; IC-serialized after
            // the gating flag loads).
            const unsigned long long* src = reinterpret_cast<const unsigned long long*>(
                &hxc[((size_t)(tg&1)*B_ + b0) * H_]);      // 512 ull, 2 batches
            #pragma unroll
            for (int i = 0; i < 2; ++i) {
                int e = tid + i*256;           // 0..511
                unsigned long long v = __hip_atomic_load(&src[e],
                        __ATOMIC_RELAXED, __HIP_MEMORY_SCOPE_AGENT);
                union { unsigned long long u; float f[2]; } cv; cv.u = v;
                int b = e >> 8, k = (e & 255) * 2;
                hli[(k+0)*2 + b] = cv.f[0];
                hli[(k+1)*2 + b] = cv.f[1];
            }
            __syncthreads();                               // (4)
        }
    }
}

// ------- tiny FC head -----------------------------------------------------
__global__ __launch_bounds__(64)
void fc_kernel(const float* __restrict__ hl, const float* __restrict__ fw,
               const float* __restrict__ fb, float* __restrict__ out)
{
    int b = blockIdx.x, tid = threadIdx.x;
    float p0 = 0.f, p1 = 0.f;
    #pragma unroll
    for (int i = 0; i < 8; ++i) {
        int k = tid + i*64;
        float h = hl[(size_t)b*H_ + k];
        p0 += h * fw[k];
        p1 += h * fw[H_ + k];
    }
    #pragma unroll
    for (int off = 32; off > 0; off >>= 1) {
        p0 += __shfl_down(p0, off, 64);
        p1 += __shfl_down(p1, off, 64);
    }
    if (tid == 0) {
        out[b*2+0] = p0 + fb[0];
        out[b*2+1] = p1 + fb[1];
    }
}

extern "C" void kernel_launch(void* const* d_in, const int* in_sizes, int n_in,
                              void* d_out, int out_size, void* d_ws, size_t ws_size,
                              hipStream_t stream)
{
    const float* x    = (const float*)d_in[0];
    const float* Wih0 = (const float*)d_in[1];
    const float* Whh0 = (const float*)d_in[2];
    const float* bih0 = (const float*)d_in[3];
    const float* bhh0 = (const float*)d_in[4];
    const float* Wih1 = (const float*)d_in[5];
    const float* Whh1 = (const float*)d_in[6];
    const float* bih1 = (const float*)d_in[7];
    const float* bhh1 = (const float*)d_in[8];
    const float* fcW  = (const float*)d_in[9];
    const float* fcb  = (const float*)d_in[10];
    float* out = (float*)d_out;

    // ws-adaptive chunk size (ws_size constant per session -> graph-safe).
    const size_t EXTRA = 1u << 20;
    int C = 1024;
    while (C > 16 && (2*(size_t)C*131072 + EXTRA) > ws_size) C >>= 1;
    int lgC = 0; { int t = C; while (t > 1) { t >>= 1; ++lgC; } }

    char* ws = (char*)d_ws;
    size_t S = (size_t)C * 131072;
    float*        P      = (float*)ws;          // xp0 then xp1 (per chunk)
    float*        Hc     = (float*)(ws + S);    // h1 chunk
    char*         sm     = ws + 2*S;
    float*        h2last = (float*)sm;                       // 128 KB
    float*        hxcA   = (float*)(sm + 131072);            // 256 KB (layer 0)
    float*        hxcB   = (float*)(sm + 131072 + 262144);   // 256 KB (layer 1)
    unsigned int* flags  = (unsigned int*)(sm + 131072 + 2*262144); // [2][32][8]

    const int LDS_BYTES = (32768 + 1024 + 512) * 4;   // 137216 B -> 1 block/CU
    hipFuncSetAttribute(reinterpret_cast<const void*>(rnn_scan),
                        hipFuncAttributeMaxDynamicSharedMemorySize, LDS_BYTES);

    hipMemsetAsync(flags, 0, 2048, stream);   // fresh monotonic flags per call

    const int nch = T_ / C;
    for (int c = 0; c < nch; ++c) {
        const int t0 = c * C;
        proj_gemm<256><<<dim3(C/2, 8), 256, 0, stream>>>(x, Wih0, bih0, bhh0,
                                                         P, lgC, t0, T_);
        rnn_scan<<<256, 256, LDS_BYTES, stream>>>(Whh0, P, Hc, nullptr,
                                                  hxcA, flags, t0, C);
        proj_gemm<512><<<dim3(C/2, 8), 256, 0, stream>>>(Hc, Wih1, bih1, bhh1,
                                                         P, lgC, 0, C);
        rnn_scan<<<256, 256, LDS_BYTES, stream>>>(Whh1, P, nullptr,
                                                  (c == nch-1) ? h2last : nullptr,
                                                  hxcB, flags + 256, t0, C);
    }
    fc_kernel<<<64, 64, 0, stream>>>(h2last, fcW, fcb, out);
}